// Round 1
// baseline (717.049 us; speedup 1.0000x reference)
//
#include <hip/hip_runtime.h>
#include <hip/hip_bf16.h>

#define BB 4
#define NN 4096
#define MM 4096
#define DD 128
#define BN 32
#define BM 32
#define DH 64   // d-half per block

using f32x4  = __attribute__((ext_vector_type(4))) float;
using bf16x8 = __attribute__((ext_vector_type(8))) short;

__device__ __forceinline__ short f2bf(float x) {
  union { __hip_bfloat16 h; short s; } u;
  u.h = __float2bfloat16(x);
  return u.s;
}

__device__ __forceinline__ bf16x8 pack8(const float* __restrict__ p) {
  float4 a = *(const float4*)p;
  float4 b = *(const float4*)(p + 4);
  bf16x8 r;
  r[0] = f2bf(a.x); r[1] = f2bf(a.y); r[2] = f2bf(a.z); r[3] = f2bf(a.w);
  r[4] = f2bf(b.x); r[5] = f2bf(b.y); r[6] = f2bf(b.z); r[7] = f2bf(b.w);
  return r;
}

// Fused: scores = K Q^T per batch, double softmax over batch axis (pointwise
// over the 4-vector), out = W V. Each block: 32 n-rows x one d-half, all 4
// batches (wave b owns batch b). Softmax phase redistributes so each wave
// does the across-batch softmax once for one 16x16 fragment.
__global__ __launch_bounds__(256) void attn_dot_fused(
    const float* __restrict__ k, const float* __restrict__ q,
    const float* __restrict__ v, float* __restrict__ out) {
  // s_pos: positional score exchange [b][frag][lane][reg]
  __shared__ alignas(16) float s_pos[4][4][64][4];                 // 16 KB
  __shared__ alignas(16) unsigned short Wl[4][BN][BM + 8];          // 10 KB (pad->80B rows, 16B aligned)
  __shared__ alignas(16) unsigned short VT[4][DH][BM + 8];          // 20 KB

  const int tid = threadIdx.x;
  const int wv  = tid >> 6;        // wave id == batch id in compute phases
  const int l   = tid & 63;
  const int lr  = l & 15;          // lane low  (col index in C/D layout)
  const int hg  = l >> 4;          // lane high (row group in C/D layout)
  const int n0  = blockIdx.x * BN;
  const int dh  = blockIdx.y * DH;
  const int b   = wv;

  // K A-fragments for this wave's batch: rows n0..n0+31, full D=128.
  // Assumed operand map: lane holds row (l&15), k = kf*32 + (l>>4)*8 + {0..7}.
  // (Any consistent A/B k-permutation gives correct dot products.)
  bf16x8 ka[2][4];
  for (int fi = 0; fi < 2; ++fi)
    for (int kf = 0; kf < 4; ++kf) {
      const float* p = k + ((size_t)b * NN + (n0 + fi * 16 + lr)) * DD + kf * 32 + hg * 8;
      ka[fi][kf] = pack8(p);
    }

  f32x4 acc[2][4];
  for (int fi = 0; fi < 2; ++fi)
    for (int dj = 0; dj < 4; ++dj)
      acc[fi][dj] = (f32x4){0.f, 0.f, 0.f, 0.f};

  const int fi_s = wv >> 1, fj_s = wv & 1;  // fragment owned in softmax phase

  for (int m0 = 0; m0 < MM; m0 += BM) {
    // ---- QK^T: s[b][32n][32m] ----
    bf16x8 qf[2][4];
    for (int fj = 0; fj < 2; ++fj)
      for (int kf = 0; kf < 4; ++kf) {
        const float* p = q + ((size_t)b * MM + (m0 + fj * 16 + lr)) * DD + kf * 32 + hg * 8;
        qf[fj][kf] = pack8(p);
      }
    f32x4 s[2][2];
    for (int fi = 0; fi < 2; ++fi)
      for (int fj = 0; fj < 2; ++fj)
        s[fi][fj] = (f32x4){0.f, 0.f, 0.f, 0.f};
    for (int kf = 0; kf < 4; ++kf)
      for (int fi = 0; fi < 2; ++fi)
        for (int fj = 0; fj < 2; ++fj)
          s[fi][fj] = __builtin_amdgcn_mfma_f32_16x16x32_bf16(
              ka[fi][kf], qf[fj][kf], s[fi][fj], 0, 0, 0);

    // positional write: identical (lane,reg)->(n,m) map across the 4 waves
    for (int fi = 0; fi < 2; ++fi)
      for (int fj = 0; fj < 2; ++fj)
        *(f32x4*)&s_pos[b][fi * 2 + fj][l][0] = s[fi][fj];

    // ---- stage V^T (bf16) for this wave's batch: VT[d_local][m_local] ----
    for (int j = 0; j < 8; ++j) {
      int row = j * 4 + hg;  // m_local
      const float* p = v + ((size_t)b * MM + (m0 + row)) * DD + dh + lr * 4;
      float4 vv = *(const float4*)p;
      VT[b][lr * 4 + 0][row] = (unsigned short)f2bf(vv.x);
      VT[b][lr * 4 + 1][row] = (unsigned short)f2bf(vv.y);
      VT[b][lr * 4 + 2][row] = (unsigned short)f2bf(vv.z);
      VT[b][lr * 4 + 3][row] = (unsigned short)f2bf(vv.w);
    }
    __syncthreads();

    // ---- double softmax over batch axis; wave wv handles fragment wv ----
    {
      f32x4 sv[4];
      for (int bb = 0; bb < 4; ++bb) sv[bb] = *(f32x4*)&s_pos[bb][wv][l][0];
      for (int qq = 0; qq < 4; ++qq) {
        float x0 = sv[0][qq], x1 = sv[1][qq], x2 = sv[2][qq], x3 = sv[3][qq];
        float m1 = fmaxf(fmaxf(x0, x1), fmaxf(x2, x3));
        float e0 = __expf(x0 - m1), e1 = __expf(x1 - m1);
        float e2 = __expf(x2 - m1), e3 = __expf(x3 - m1);
        float inv = __builtin_amdgcn_rcpf(e0 + e1 + e2 + e3);
        // round 2: inputs in [0,1] -> no max subtraction needed
        float f0 = __expf(e0 * inv), f1 = __expf(e1 * inv);
        float f2v = __expf(e2 * inv), f3 = __expf(e3 * inv);
        float inv2 = __builtin_amdgcn_rcpf(f0 + f1 + f2v + f3);
        // C/D layout (HW-verified): row = hg*4+reg, col = lr
        int n_loc = fi_s * 16 + hg * 4 + qq;
        int m_loc = fj_s * 16 + lr;
        Wl[0][n_loc][m_loc] = (unsigned short)f2bf(f0 * inv2);
        Wl[1][n_loc][m_loc] = (unsigned short)f2bf(f1 * inv2);
        Wl[2][n_loc][m_loc] = (unsigned short)f2bf(f2v * inv2);
        Wl[3][n_loc][m_loc] = (unsigned short)f2bf(f3 * inv2);
      }
    }
    __syncthreads();

    // ---- PV: acc[n 32][d 64] += W(32x32) @ V(32x64) ----
    bf16x8 wa[2], vbf[4];
    for (int fi = 0; fi < 2; ++fi)
      wa[fi] = *(bf16x8*)&Wl[b][fi * 16 + lr][hg * 8];
    for (int dj = 0; dj < 4; ++dj)
      vbf[dj] = *(bf16x8*)&VT[b][dj * 16 + lr][hg * 8];
    for (int fi = 0; fi < 2; ++fi)
      for (int dj = 0; dj < 4; ++dj)
        acc[fi][dj] = __builtin_amdgcn_mfma_f32_16x16x32_bf16(
            wa[fi], vbf[dj], acc[fi][dj], 0, 0, 0);
    __syncthreads();  // protect s_pos/Wl/VT before next iteration overwrites
  }

  // ---- epilogue: C/D layout -> global fp32 ----
  for (int fi = 0; fi < 2; ++fi)
    for (int dj = 0; dj < 4; ++dj)
      for (int qq = 0; qq < 4; ++qq)
        out[((size_t)b * NN + (n0 + fi * 16 + hg * 4 + qq)) * DD + dh + dj * 16 + lr] =
            acc[fi][dj][qq];
}

extern "C" void kernel_launch(void* const* d_in, const int* in_sizes, int n_in,
                              void* d_out, int out_size, void* d_ws, size_t ws_size,
                              hipStream_t stream) {
  (void)in_sizes; (void)n_in; (void)out_size; (void)d_ws; (void)ws_size;
  const float* k = (const float*)d_in[0];
  const float* q = (const float*)d_in[1];
  const float* v = (const float*)d_in[2];
  float* out = (float*)d_out;
  dim3 grid(NN / BN, 2);
  dim3 block(256);
  hipLaunchKernelGGL(attn_dot_fused, grid, block, 0, stream, k, q, v, out);
}

// Round 2
// 219.081 us; speedup vs baseline: 3.2730x; 3.2730x over previous
//
#include <hip/hip_runtime.h>
#include <hip/hip_bf16.h>

#define NB 4
#define NN 4096
#define MM 4096
#define DD 128
#define BN 32
#define BM 64
#define NCH 6   // m-chunks -> grid 128*6=768 blocks = 3/CU at 48KB LDS

using f32x4  = __attribute__((ext_vector_type(4))) float;
using bf16x8 = __attribute__((ext_vector_type(8))) short;

__device__ __forceinline__ short f2bf(float x) {
  union { __hip_bfloat16 h; short s; } u;
  u.h = __float2bfloat16(x);
  return u.s;
}

__device__ __forceinline__ bf16x8 pack8(const float* __restrict__ p) {
  float4 a = *(const float4*)p;
  float4 b = *(const float4*)(p + 4);
  bf16x8 r;
  r[0] = f2bf(a.x); r[1] = f2bf(a.y); r[2] = f2bf(a.z); r[3] = f2bf(a.w);
  r[4] = f2bf(b.x); r[5] = f2bf(b.y); r[6] = f2bf(b.z); r[7] = f2bf(b.w);
  return r;
}

__global__ __launch_bounds__(256) void zero_out_kernel(float4* __restrict__ out) {
  out[(size_t)blockIdx.x * 256 + threadIdx.x] = (float4){0.f, 0.f, 0.f, 0.f};
}

__global__ __launch_bounds__(256) void cvt_bf16_kernel(const float* __restrict__ src,
                                                       unsigned short* __restrict__ dst) {
  size_t i = ((size_t)blockIdx.x * 256 + threadIdx.x) * 8;
  bf16x8 r = pack8(src + i);
  *(bf16x8*)(dst + i) = r;
}

// V[b][m][d] fp32 -> Vt[b][d][m] bf16, 64x64 tiles via LDS
__global__ __launch_bounds__(256) void transpose_v_kernel(const float* __restrict__ v,
                                                          unsigned short* __restrict__ vt) {
  __shared__ unsigned short t[64][72];  // pad 72 (144B rows, 16B-aligned)
  const int b = blockIdx.z, d0 = blockIdx.y * 64, m0 = blockIdx.x * 64;
  const int r = threadIdx.x >> 2, c4 = threadIdx.x & 3;
  const float* src = v + ((size_t)b * MM + m0 + r) * DD + d0 + c4 * 16;
  for (int j = 0; j < 4; ++j) {
    float4 x = *(const float4*)(src + j * 4);
    int dl = c4 * 16 + j * 4;
    t[dl + 0][r] = (unsigned short)f2bf(x.x);
    t[dl + 1][r] = (unsigned short)f2bf(x.y);
    t[dl + 2][r] = (unsigned short)f2bf(x.z);
    t[dl + 3][r] = (unsigned short)f2bf(x.w);
  }
  __syncthreads();
  const int d = threadIdx.x >> 2, seg = threadIdx.x & 3;
  unsigned short* dst = vt + ((size_t)b * DD + d0 + d) * MM + m0 + seg * 16;
  *(bf16x8*)dst = *(bf16x8*)&t[d][seg * 16];
  *(bf16x8*)(dst + 8) = *(bf16x8*)&t[d][seg * 16 + 8];
}

// Fused: per block, n-tile of 32 x all 4 batches, m-chunk loop (BM=64/step).
// 8 waves: QK phase wave=(b, m-half); softmax phase wave=one 16x16 frag slot
// for all 4 batches; PV phase wave=(b, d-half). Partial out via atomicAdd.
template <bool WS>
__global__ __launch_bounds__(512, 6) void attn_fused(
    const float* __restrict__ k, const float* __restrict__ q, const float* __restrict__ v,
    const unsigned short* __restrict__ qb, const unsigned short* __restrict__ vt,
    float* __restrict__ out) {
  __shared__ alignas(16) float s_pos[NB][8][64][4];          // 32 KB positional exchange
  __shared__ alignas(16) unsigned short Wl[NB][BN][BM];      // 16 KB, m XOR-swizzled

  const int tid = threadIdx.x;
  const int wv = tid >> 6, l = tid & 63, lr = l & 15, hg = l >> 4;
  const int n0 = blockIdx.x * BN;
  const int cid = blockIdx.y;
  const int it0 = (cid * (MM / BM)) / NCH;
  const int it1 = ((cid + 1) * (MM / BM)) / NCH;

  const int bq = wv >> 1, h = wv & 1;  // (batch, half) for QK and PV phases
  // softmax phase: slot wv = h_s*4 + fi_s*2 + fj_s
  const int h_s = wv >> 2, fi_s = (wv >> 1) & 1, fj_s = wv & 1;

  // K A-fragments (register-cached): rows n0..n0+31 of batch bq, full D
  bf16x8 ka[2][4];
  for (int fi = 0; fi < 2; ++fi)
    for (int kf = 0; kf < 4; ++kf)
      ka[fi][kf] = pack8(k + ((size_t)bq * NN + n0 + fi * 16 + lr) * DD + kf * 32 + hg * 8);

  f32x4 acc[2][4];
  for (int fi = 0; fi < 2; ++fi)
    for (int dj = 0; dj < 4; ++dj) acc[fi][dj] = (f32x4){0.f, 0.f, 0.f, 0.f};

  for (int it = it0; it < it1; ++it) {
    const int m0 = it * BM;

    // ---- QK^T: wave (bq,h) computes S[bq][0..32n][h*32..+32m] ----
    bf16x8 qf[2][4];
    for (int fj = 0; fj < 2; ++fj)
      for (int kf = 0; kf < 4; ++kf) {
        size_t moff = ((size_t)bq * MM + m0 + h * 32 + fj * 16 + lr) * DD + kf * 32 + hg * 8;
        if (WS) qf[fj][kf] = *(const bf16x8*)(qb + moff);
        else    qf[fj][kf] = pack8(q + moff);
      }
    f32x4 s[2][2];
    for (int fi = 0; fi < 2; ++fi)
      for (int fj = 0; fj < 2; ++fj) s[fi][fj] = (f32x4){0.f, 0.f, 0.f, 0.f};
    for (int kf = 0; kf < 4; ++kf)
      for (int fi = 0; fi < 2; ++fi)
        for (int fj = 0; fj < 2; ++fj)
          s[fi][fj] = __builtin_amdgcn_mfma_f32_16x16x32_bf16(ka[fi][kf], qf[fj][kf],
                                                              s[fi][fj], 0, 0, 0);
    for (int fi = 0; fi < 2; ++fi)
      for (int fj = 0; fj < 2; ++fj)
        *(f32x4*)&s_pos[bq][h * 4 + fi * 2 + fj][l][0] = s[fi][fj];
    __syncthreads();

    // ---- double softmax over batch axis (pointwise per (n,m)) ----
    {
      f32x4 sv[NB];
      for (int bb = 0; bb < NB; ++bb) sv[bb] = *(f32x4*)&s_pos[bb][wv][l][0];
      for (int qq = 0; qq < 4; ++qq) {
        float x0 = sv[0][qq], x1 = sv[1][qq], x2 = sv[2][qq], x3 = sv[3][qq];
        float m1 = fmaxf(fmaxf(x0, x1), fmaxf(x2, x3));
        float e0 = __expf(x0 - m1), e1 = __expf(x1 - m1);
        float e2 = __expf(x2 - m1), e3 = __expf(x3 - m1);
        float inv = __builtin_amdgcn_rcpf(e0 + e1 + e2 + e3);
        float f0 = __expf(e0 * inv), f1 = __expf(e1 * inv);
        float f2v = __expf(e2 * inv), f3 = __expf(e3 * inv);
        float inv2 = __builtin_amdgcn_rcpf(f0 + f1 + f2v + f3);
        const int n_loc = fi_s * 16 + hg * 4 + qq;          // C/D layout: row
        const int m_loc = h_s * 32 + fj_s * 16 + lr;        // C/D layout: col
        const int msw = m_loc ^ ((n_loc & 7) << 3);         // 16B-chunk XOR swizzle
        Wl[0][n_loc][msw] = (unsigned short)f2bf(f0 * inv2);
        Wl[1][n_loc][msw] = (unsigned short)f2bf(f1 * inv2);
        Wl[2][n_loc][msw] = (unsigned short)f2bf(f2v * inv2);
        Wl[3][n_loc][msw] = (unsigned short)f2bf(f3 * inv2);
      }
    }
    __syncthreads();

    // ---- PV: wave (bq,h) accumulates out[bq][32n][h*64..+64d] ----
    bf16x8 wf[2][2], vf[4][2];
    for (int fi = 0; fi < 2; ++fi)
      for (int kf = 0; kf < 2; ++kf) {
        const int row = fi * 16 + lr, mo = kf * 32 + hg * 8;
        wf[fi][kf] = *(bf16x8*)&Wl[bq][row][mo ^ ((row & 7) << 3)];
      }
    for (int dj = 0; dj < 4; ++dj)
      for (int kf = 0; kf < 2; ++kf) {
        if (WS) {
          vf[dj][kf] = *(const bf16x8*)(vt + ((size_t)bq * DD + h * 64 + dj * 16 + lr) * MM +
                                        m0 + kf * 32 + hg * 8);
        } else {
          bf16x8 t;
          for (int e = 0; e < 8; ++e)
            t[e] = f2bf(v[((size_t)bq * MM + m0 + kf * 32 + hg * 8 + e) * DD +
                          h * 64 + dj * 16 + lr]);
          vf[dj][kf] = t;
        }
      }
    for (int kf = 0; kf < 2; ++kf)
      for (int fi = 0; fi < 2; ++fi)
        for (int dj = 0; dj < 4; ++dj)
          acc[fi][dj] = __builtin_amdgcn_mfma_f32_16x16x32_bf16(wf[fi][kf], vf[dj][kf],
                                                                acc[fi][dj], 0, 0, 0);
    __syncthreads();  // protect s_pos/Wl before next iteration
  }

  // ---- epilogue: partial-sum into out ----
  for (int fi = 0; fi < 2; ++fi)
    for (int dj = 0; dj < 4; ++dj)
      for (int qq = 0; qq < 4; ++qq)
        atomicAdd(out + ((size_t)bq * NN + n0 + fi * 16 + hg * 4 + qq) * DD +
                      h * 64 + dj * 16 + lr,
                  acc[fi][dj][qq]);
}

extern "C" void kernel_launch(void* const* d_in, const int* in_sizes, int n_in,
                              void* d_out, int out_size, void* d_ws, size_t ws_size,
                              hipStream_t stream) {
  (void)in_sizes; (void)n_in; (void)out_size;
  const float* k = (const float*)d_in[0];
  const float* q = (const float*)d_in[1];
  const float* v = (const float*)d_in[2];
  float* out = (float*)d_out;

  const size_t q_elems = (size_t)NB * MM * DD;            // 2M bf16 = 4 MB
  const size_t need = 2 * q_elems * sizeof(unsigned short);  // Q + Vt
  const bool use_ws = (d_ws != nullptr) && (ws_size >= need);

  // zero-init out (harness poisons it; atomics accumulate)
  zero_out_kernel<<<(NB * NN * DD) / 4 / 256, 256, 0, stream>>>((float4*)out);

  if (use_ws) {
    unsigned short* qb = (unsigned short*)d_ws;
    unsigned short* vtp = qb + q_elems;
    cvt_bf16_kernel<<<q_elems / 8 / 256, 256, 0, stream>>>(q, qb);
    transpose_v_kernel<<<dim3(MM / 64, DD / 64, NB), 256, 0, stream>>>(v, vtp);
    attn_fused<true><<<dim3(NN / BN, NCH), 512, 0, stream>>>(k, q, v, qb, vtp, out);
  } else {
    attn_fused<false><<<dim3(NN / BN, NCH), 512, 0, stream>>>(k, q, v, nullptr, nullptr, out);
  }
}

// Round 3
// 171.825 us; speedup vs baseline: 4.1731x; 1.2750x over previous
//
#include <hip/hip_runtime.h>
#include <hip/hip_bf16.h>

#define NB 4
#define NN 4096
#define MM 4096
#define DD 128
#define BN 32
#define BM 64
#define NCH 4   // m-chunks; grid = 128*4 = 512 blocks, XCD-pinned

using f32x4  = __attribute__((ext_vector_type(4))) float;
using bf16x8 = __attribute__((ext_vector_type(8))) short;

__device__ __forceinline__ short f2bf(float x) {
  union { __hip_bfloat16 h; short s; } u;
  u.h = __float2bfloat16(x);
  return u.s;
}

__device__ __forceinline__ bf16x8 pack8(const float* __restrict__ p) {
  float4 a = *(const float4*)p;
  float4 b = *(const float4*)(p + 4);
  bf16x8 r;
  r[0] = f2bf(a.x); r[1] = f2bf(a.y); r[2] = f2bf(a.z); r[3] = f2bf(a.w);
  r[4] = f2bf(b.x); r[5] = f2bf(b.y); r[6] = f2bf(b.z); r[7] = f2bf(b.w);
  return r;
}

__global__ __launch_bounds__(256) void zero_out_kernel(float4* __restrict__ out) {
  out[(size_t)blockIdx.x * 256 + threadIdx.x] = (float4){0.f, 0.f, 0.f, 0.f};
}

__global__ __launch_bounds__(256) void cvt_bf16_kernel(const float* __restrict__ src,
                                                       unsigned short* __restrict__ dst) {
  size_t i = ((size_t)blockIdx.x * 256 + threadIdx.x) * 8;
  *(bf16x8*)(dst + i) = pack8(src + i);
}

// V[b][m][d] fp32 -> Vt[b][d][m] bf16, 64x64 tiles via LDS
__global__ __launch_bounds__(256) void transpose_v_kernel(const float* __restrict__ v,
                                                          unsigned short* __restrict__ vt) {
  __shared__ unsigned short t[64][72];
  const int b = blockIdx.z, d0 = blockIdx.y * 64, m0 = blockIdx.x * 64;
  const int r = threadIdx.x >> 2, c4 = threadIdx.x & 3;
  const float* src = v + ((size_t)b * MM + m0 + r) * DD + d0 + c4 * 16;
  for (int j = 0; j < 4; ++j) {
    float4 x = *(const float4*)(src + j * 4);
    int dl = c4 * 16 + j * 4;
    t[dl + 0][r] = (unsigned short)f2bf(x.x);
    t[dl + 1][r] = (unsigned short)f2bf(x.y);
    t[dl + 2][r] = (unsigned short)f2bf(x.z);
    t[dl + 3][r] = (unsigned short)f2bf(x.w);
  }
  __syncthreads();
  const int d = threadIdx.x >> 2, seg = threadIdx.x & 3;
  unsigned short* dst = vt + ((size_t)b * DD + d0 + d) * MM + m0 + seg * 16;
  *(bf16x8*)dst = *(bf16x8*)&t[d][seg * 16];
  *(bf16x8*)(dst + 8) = *(bf16x8*)&t[d][seg * 16 + 8];
}

// Fused main kernel. 1-D grid, XCD-pinned: cid = wg&3, n0 = (wg>>2)*32.
// XCD = wg%8 -> XCDs i and i+4 exclusively own m-chunk i%4 (n even/odd split),
// so each XCD's L2 holds its K-slice(2MB) + Q-slice(1MB) + Vt-slice(1MB).
template <bool WS>
__global__ __launch_bounds__(512, 4) void attn_fused(
    const float* __restrict__ k, const float* __restrict__ q, const float* __restrict__ v,
    const unsigned short* __restrict__ kb, const unsigned short* __restrict__ qb,
    const unsigned short* __restrict__ vt, float* __restrict__ out) {
  __shared__ alignas(16) float s_pos[NB][8][64][4];          // 32 KB positional exchange
  __shared__ alignas(16) unsigned short Wl[NB][BN][BM];      // 16 KB, m XOR-swizzled

  const int tid = threadIdx.x;
  const int wv = tid >> 6, l = tid & 63, lr = l & 15, hg = l >> 4;
  const int wg = blockIdx.x;
  const int cid = wg & (NCH - 1);
  const int n0 = (wg >> 2) * BN;
  const int it0 = cid * (MM / BM / NCH);
  const int it1 = it0 + (MM / BM / NCH);

  const int bq = wv >> 1, h = wv & 1;          // (batch, half) for QK/PV phases
  const int h_s = wv >> 2, fi_s = (wv >> 1) & 1, fj_s = wv & 1;  // softmax slot

  // K A-fragments (register-cached): rows n0..n0+31 of batch bq, full D
  bf16x8 ka[2][4];
  for (int fi = 0; fi < 2; ++fi)
    for (int kf = 0; kf < 4; ++kf) {
      size_t koff = ((size_t)bq * NN + n0 + fi * 16 + lr) * DD + kf * 32 + hg * 8;
      if (WS) ka[fi][kf] = *(const bf16x8*)(kb + koff);
      else    ka[fi][kf] = pack8(k + koff);
    }

  f32x4 acc[2][4];
  for (int fi = 0; fi < 2; ++fi)
    for (int dj = 0; dj < 4; ++dj) acc[fi][dj] = (f32x4){0.f, 0.f, 0.f, 0.f};

  for (int it = it0; it < it1; ++it) {
    const int m0 = it * BM;

    // ---- QK^T: wave (bq,h) computes S[bq][0..32n][h*32..+32m] ----
    bf16x8 qf[2][4];
    for (int fj = 0; fj < 2; ++fj)
      for (int kf = 0; kf < 4; ++kf) {
        size_t moff = ((size_t)bq * MM + m0 + h * 32 + fj * 16 + lr) * DD + kf * 32 + hg * 8;
        if (WS) qf[fj][kf] = *(const bf16x8*)(qb + moff);
        else    qf[fj][kf] = pack8(q + moff);
      }
    f32x4 s[2][2];
    for (int fi = 0; fi < 2; ++fi)
      for (int fj = 0; fj < 2; ++fj) s[fi][fj] = (f32x4){0.f, 0.f, 0.f, 0.f};
    for (int kf = 0; kf < 4; ++kf)
      for (int fi = 0; fi < 2; ++fi)
        for (int fj = 0; fj < 2; ++fj)
          s[fi][fj] = __builtin_amdgcn_mfma_f32_16x16x32_bf16(ka[fi][kf], qf[fj][kf],
                                                              s[fi][fj], 0, 0, 0);
    for (int fi = 0; fi < 2; ++fi)
      for (int fj = 0; fj < 2; ++fj)
        *(f32x4*)&s_pos[bq][h * 4 + fi * 2 + fj][l][0] = s[fi][fj];
    __syncthreads();

    // ---- double softmax over batch axis (pointwise per (n,m)) ----
    {
      f32x4 sv[NB];
      for (int bb = 0; bb < NB; ++bb) sv[bb] = *(f32x4*)&s_pos[bb][wv][l][0];
      for (int qq = 0; qq < 4; ++qq) {
        float x0 = sv[0][qq], x1 = sv[1][qq], x2 = sv[2][qq], x3 = sv[3][qq];
        float m1 = fmaxf(fmaxf(x0, x1), fmaxf(x2, x3));
        float e0 = __expf(x0 - m1), e1 = __expf(x1 - m1);
        float e2 = __expf(x2 - m1), e3 = __expf(x3 - m1);
        float inv = __builtin_amdgcn_rcpf(e0 + e1 + e2 + e3);
        float f0 = __expf(e0 * inv), f1 = __expf(e1 * inv);
        float f2v = __expf(e2 * inv), f3 = __expf(e3 * inv);
        float inv2 = __builtin_amdgcn_rcpf(f0 + f1 + f2v + f3);
        const int n_loc = fi_s * 16 + hg * 4 + qq;          // C/D layout: row
        const int m_loc = h_s * 32 + fj_s * 16 + lr;        // C/D layout: col
        const int msw = m_loc ^ ((n_loc & 7) << 3);         // 16B-chunk XOR swizzle
        Wl[0][n_loc][msw] = (unsigned short)f2bf(f0 * inv2);
        Wl[1][n_loc][msw] = (unsigned short)f2bf(f1 * inv2);
        Wl[2][n_loc][msw] = (unsigned short)f2bf(f2v * inv2);
        Wl[3][n_loc][msw] = (unsigned short)f2bf(f3 * inv2);
      }
    }
    __syncthreads();

    // ---- PV: wave (bq,h) accumulates out[bq][32n][h*64..+64d] ----
    bf16x8 wf[2][2], vf[4][2];
    for (int dj = 0; dj < 4; ++dj)
      for (int kf = 0; kf < 2; ++kf) {
        if (WS) {
          vf[dj][kf] = *(const bf16x8*)(vt + ((size_t)bq * DD + h * 64 + dj * 16 + lr) * MM +
                                        m0 + kf * 32 + hg * 8);
        } else {
          bf16x8 t;
          for (int e = 0; e < 8; ++e)
            t[e] = f2bf(v[((size_t)bq * MM + m0 + kf * 32 + hg * 8 + e) * DD +
                          h * 64 + dj * 16 + lr]);
          vf[dj][kf] = t;
        }
      }
    for (int fi = 0; fi < 2; ++fi)
      for (int kf = 0; kf < 2; ++kf) {
        const int row = fi * 16 + lr, mo = kf * 32 + hg * 8;
        wf[fi][kf] = *(bf16x8*)&Wl[bq][row][mo ^ ((row & 7) << 3)];
      }
    for (int kf = 0; kf < 2; ++kf)
      for (int fi = 0; fi < 2; ++fi)
        for (int dj = 0; dj < 4; ++dj)
          acc[fi][dj] = __builtin_amdgcn_mfma_f32_16x16x32_bf16(wf[fi][kf], vf[dj][kf],
                                                                acc[fi][dj], 0, 0, 0);
    __syncthreads();  // protect s_pos/Wl before next iteration
  }

  // ---- epilogue: partial-sum into out (4 chunks collide) ----
  for (int fi = 0; fi < 2; ++fi)
    for (int dj = 0; dj < 4; ++dj)
      for (int qq = 0; qq < 4; ++qq)
        atomicAdd(out + ((size_t)bq * NN + n0 + fi * 16 + hg * 4 + qq) * DD +
                      h * 64 + dj * 16 + lr,
                  acc[fi][dj][qq]);
}

extern "C" void kernel_launch(void* const* d_in, const int* in_sizes, int n_in,
                              void* d_out, int out_size, void* d_ws, size_t ws_size,
                              hipStream_t stream) {
  (void)in_sizes; (void)n_in; (void)out_size;
  const float* k = (const float*)d_in[0];
  const float* q = (const float*)d_in[1];
  const float* v = (const float*)d_in[2];
  float* out = (float*)d_out;

  const size_t elems = (size_t)NB * MM * DD;                 // 2M per tensor
  const size_t need = 3 * elems * sizeof(unsigned short);    // kb + qb + vt = 12 MB
  const bool use_ws = (d_ws != nullptr) && (ws_size >= need);

  zero_out_kernel<<<(NB * NN * DD) / 4 / 256, 256, 0, stream>>>((float4*)out);

  if (use_ws) {
    unsigned short* kb = (unsigned short*)d_ws;
    unsigned short* qb = kb + elems;
    unsigned short* vtp = qb + elems;
    cvt_bf16_kernel<<<elems / 8 / 256, 256, 0, stream>>>(k, kb);
    cvt_bf16_kernel<<<elems / 8 / 256, 256, 0, stream>>>(q, qb);
    transpose_v_kernel<<<dim3(MM / 64, DD / 64, NB), 256, 0, stream>>>(v, vtp);
    attn_fused<true><<<dim3(NN / BN * NCH), 512, 0, stream>>>(k, q, v, kb, qb, vtp, out);
  } else {
    attn_fused<false><<<dim3(NN / BN * NCH), 512, 0, stream>>>(k, q, v, nullptr, nullptr,
                                                               nullptr, out);
  }
}

// Round 4
// 153.621 us; speedup vs baseline: 4.6676x; 1.1185x over previous
//
#include <hip/hip_runtime.h>
#include <hip/hip_bf16.h>

#define NB 4
#define NN 4096
#define MM 4096
#define DD 128
#define BN 32
#define BM 64
#define NCH 4   // m-chunks; grid = 128*4 = 512 blocks, XCD-pinned
#define OUT_ELEMS ((size_t)NB * NN * DD)

using f32x4  = __attribute__((ext_vector_type(4))) float;
using bf16x8 = __attribute__((ext_vector_type(8))) short;

__device__ __forceinline__ short f2bf(float x) {
  union { __hip_bfloat16 h; short s; } u;
  u.h = __float2bfloat16(x);
  return u.s;
}

__device__ __forceinline__ bf16x8 pack8(const float* __restrict__ p) {
  float4 a = *(const float4*)p;
  float4 b = *(const float4*)(p + 4);
  bf16x8 r;
  r[0] = f2bf(a.x); r[1] = f2bf(a.y); r[2] = f2bf(a.z); r[3] = f2bf(a.w);
  r[4] = f2bf(b.x); r[5] = f2bf(b.y); r[6] = f2bf(b.z); r[7] = f2bf(b.w);
  return r;
}

__global__ __launch_bounds__(256) void zero_out_kernel(float4* __restrict__ out) {
  out[(size_t)blockIdx.x * 256 + threadIdx.x] = (float4){0.f, 0.f, 0.f, 0.f};
}

__global__ __launch_bounds__(256) void cvt_bf16_kernel(const float* __restrict__ src,
                                                       unsigned short* __restrict__ dst) {
  size_t i = ((size_t)blockIdx.x * 256 + threadIdx.x) * 8;
  *(bf16x8*)(dst + i) = pack8(src + i);
}

// V[b][m][d] fp32 -> Vt[b][d][m] bf16, 64x64 tiles via LDS
__global__ __launch_bounds__(256) void transpose_v_kernel(const float* __restrict__ v,
                                                          unsigned short* __restrict__ vt) {
  __shared__ unsigned short t[64][72];
  const int b = blockIdx.z, d0 = blockIdx.y * 64, m0 = blockIdx.x * 64;
  const int r = threadIdx.x >> 2, c4 = threadIdx.x & 3;
  const float* src = v + ((size_t)b * MM + m0 + r) * DD + d0 + c4 * 16;
  for (int j = 0; j < 4; ++j) {
    float4 x = *(const float4*)(src + j * 4);
    int dl = c4 * 16 + j * 4;
    t[dl + 0][r] = (unsigned short)f2bf(x.x);
    t[dl + 1][r] = (unsigned short)f2bf(x.y);
    t[dl + 2][r] = (unsigned short)f2bf(x.z);
    t[dl + 3][r] = (unsigned short)f2bf(x.w);
  }
  __syncthreads();
  const int d = threadIdx.x >> 2, seg = threadIdx.x & 3;
  unsigned short* dst = vt + ((size_t)b * DD + d0 + d) * MM + m0 + seg * 16;
  *(bf16x8*)dst = *(bf16x8*)&t[d][seg * 16];
  *(bf16x8*)(dst + 8) = *(bf16x8*)&t[d][seg * 16 + 8];
}

// Sum the NCH partial tensors -> out
__global__ __launch_bounds__(256) void reduce4_kernel(const float* __restrict__ p,
                                                      float* __restrict__ out) {
  size_t i = ((size_t)blockIdx.x * 256 + threadIdx.x) * 4;
  float4 a = *(const float4*)(p + i);
  float4 b = *(const float4*)(p + OUT_ELEMS + i);
  float4 c = *(const float4*)(p + 2 * OUT_ELEMS + i);
  float4 d = *(const float4*)(p + 3 * OUT_ELEMS + i);
  float4 r;
  r.x = (a.x + b.x) + (c.x + d.x);
  r.y = (a.y + b.y) + (c.y + d.y);
  r.z = (a.z + b.z) + (c.z + d.z);
  r.w = (a.w + b.w) + (c.w + d.w);
  *(float4*)(out + i) = r;
}

// Fused main kernel. 1-D grid, XCD-pinned: cid = wg&3, n0 = (wg>>2)*32.
// PART: store per-chunk partials to ws (reduced later); else atomicAdd to out.
template <bool WS, bool PART>
__global__ __launch_bounds__(512, 4) void attn_fused(
    const float* __restrict__ k, const float* __restrict__ q, const float* __restrict__ v,
    const unsigned short* __restrict__ kb, const unsigned short* __restrict__ qb,
    const unsigned short* __restrict__ vt, float* __restrict__ outp) {
  __shared__ alignas(16) float s_pos[NB][8][64][4];          // 32 KB positional exchange
  __shared__ alignas(16) unsigned short Wl[NB][BN][BM];      // 16 KB, m XOR-swizzled

  const int tid = threadIdx.x;
  const int wv = tid >> 6, l = tid & 63, lr = l & 15, hg = l >> 4;
  const int wg = blockIdx.x;
  const int cid = wg & (NCH - 1);
  const int n0 = (wg >> 2) * BN;
  const int it0 = cid * (MM / BM / NCH);
  const int it1 = it0 + (MM / BM / NCH);

  const int bq = wv >> 1, h = wv & 1;          // (batch, half) for QK/PV phases
  const int h_s = wv >> 2, fi_s = (wv >> 1) & 1, fj_s = wv & 1;  // softmax slot

  // K A-fragments (register-cached): rows n0..n0+31 of batch bq, full D
  bf16x8 ka[2][4];
  for (int fi = 0; fi < 2; ++fi)
    for (int kf = 0; kf < 4; ++kf) {
      size_t koff = ((size_t)bq * NN + n0 + fi * 16 + lr) * DD + kf * 32 + hg * 8;
      if (WS) ka[fi][kf] = *(const bf16x8*)(kb + koff);
      else    ka[fi][kf] = pack8(k + koff);
    }

  f32x4 acc[2][4];
  for (int fi = 0; fi < 2; ++fi)
    for (int dj = 0; dj < 4; ++dj) acc[fi][dj] = (f32x4){0.f, 0.f, 0.f, 0.f};

  for (int it = it0; it < it1; ++it) {
    const int m0 = it * BM;

    // ---- QK^T: wave (bq,h) computes S[bq][0..32n][h*32..+32m] ----
    bf16x8 qf[2][4];
    for (int fj = 0; fj < 2; ++fj)
      for (int kf = 0; kf < 4; ++kf) {
        size_t moff = ((size_t)bq * MM + m0 + h * 32 + fj * 16 + lr) * DD + kf * 32 + hg * 8;
        if (WS) qf[fj][kf] = *(const bf16x8*)(qb + moff);
        else    qf[fj][kf] = pack8(q + moff);
      }
    f32x4 s[2][2];
    for (int fi = 0; fi < 2; ++fi)
      for (int fj = 0; fj < 2; ++fj) s[fi][fj] = (f32x4){0.f, 0.f, 0.f, 0.f};
    for (int kf = 0; kf < 4; ++kf)
      for (int fi = 0; fi < 2; ++fi)
        for (int fj = 0; fj < 2; ++fj)
          s[fi][fj] = __builtin_amdgcn_mfma_f32_16x16x32_bf16(ka[fi][kf], qf[fj][kf],
                                                              s[fi][fj], 0, 0, 0);
    for (int fi = 0; fi < 2; ++fi)
      for (int fj = 0; fj < 2; ++fj)
        *(f32x4*)&s_pos[bq][h * 4 + fi * 2 + fj][l][0] = s[fi][fj];

    // ---- V fragments issued EARLY: latency hides under barrier + softmax ----
    bf16x8 vf[4][2];
    for (int dj = 0; dj < 4; ++dj)
      for (int kf = 0; kf < 2; ++kf) {
        if (WS) {
          vf[dj][kf] = *(const bf16x8*)(vt + ((size_t)bq * DD + h * 64 + dj * 16 + lr) * MM +
                                        m0 + kf * 32 + hg * 8);
        } else {
          bf16x8 t;
          for (int e = 0; e < 8; ++e)
            t[e] = f2bf(v[((size_t)bq * MM + m0 + kf * 32 + hg * 8 + e) * DD +
                          h * 64 + dj * 16 + lr]);
          vf[dj][kf] = t;
        }
      }
    __syncthreads();

    // ---- double softmax over batch axis (pointwise per (n,m)) ----
    {
      f32x4 sv[NB];
      for (int bb = 0; bb < NB; ++bb) sv[bb] = *(f32x4*)&s_pos[bb][wv][l][0];
      for (int qq = 0; qq < 4; ++qq) {
        float x0 = sv[0][qq], x1 = sv[1][qq], x2 = sv[2][qq], x3 = sv[3][qq];
        float m1 = fmaxf(fmaxf(x0, x1), fmaxf(x2, x3));
        float e0 = __expf(x0 - m1), e1 = __expf(x1 - m1);
        float e2 = __expf(x2 - m1), e3 = __expf(x3 - m1);
        float inv = __builtin_amdgcn_rcpf(e0 + e1 + e2 + e3);
        float f0 = __expf(e0 * inv), f1 = __expf(e1 * inv);
        float f2v = __expf(e2 * inv), f3 = __expf(e3 * inv);
        float inv2 = __builtin_amdgcn_rcpf(f0 + f1 + f2v + f3);
        const int n_loc = fi_s * 16 + hg * 4 + qq;          // C/D layout: row
        const int m_loc = h_s * 32 + fj_s * 16 + lr;        // C/D layout: col
        const int msw = m_loc ^ ((n_loc & 7) << 3);         // 16B-chunk XOR swizzle
        Wl[0][n_loc][msw] = (unsigned short)f2bf(f0 * inv2);
        Wl[1][n_loc][msw] = (unsigned short)f2bf(f1 * inv2);
        Wl[2][n_loc][msw] = (unsigned short)f2bf(f2v * inv2);
        Wl[3][n_loc][msw] = (unsigned short)f2bf(f3 * inv2);
      }
    }
    __syncthreads();

    // ---- PV: wave (bq,h) accumulates out[bq][32n][h*64..+64d] ----
    bf16x8 wf[2][2];
    for (int fi = 0; fi < 2; ++fi)
      for (int kf = 0; kf < 2; ++kf) {
        const int row = fi * 16 + lr, mo = kf * 32 + hg * 8;
        wf[fi][kf] = *(bf16x8*)&Wl[bq][row][mo ^ ((row & 7) << 3)];
      }
    for (int kf = 0; kf < 2; ++kf)
      for (int fi = 0; fi < 2; ++fi)
        for (int dj = 0; dj < 4; ++dj)
          acc[fi][dj] = __builtin_amdgcn_mfma_f32_16x16x32_bf16(wf[fi][kf], vf[dj][kf],
                                                                acc[fi][dj], 0, 0, 0);
    __syncthreads();  // protect s_pos/Wl before next iteration
  }

  // ---- epilogue ----
  float* dst = PART ? (outp + (size_t)cid * OUT_ELEMS) : outp;
  for (int fi = 0; fi < 2; ++fi)
    for (int dj = 0; dj < 4; ++dj)
      for (int qq = 0; qq < 4; ++qq) {
        size_t off = ((size_t)bq * NN + n0 + fi * 16 + hg * 4 + qq) * DD +
                     h * 64 + dj * 16 + lr;
        if (PART) dst[off] = acc[fi][dj][qq];
        else      atomicAdd(dst + off, acc[fi][dj][qq]);
      }
}

extern "C" void kernel_launch(void* const* d_in, const int* in_sizes, int n_in,
                              void* d_out, int out_size, void* d_ws, size_t ws_size,
                              hipStream_t stream) {
  (void)in_sizes; (void)n_in; (void)out_size;
  const float* k = (const float*)d_in[0];
  const float* q = (const float*)d_in[1];
  const float* v = (const float*)d_in[2];
  float* out = (float*)d_out;

  const size_t elems = (size_t)NB * MM * DD;                    // 2M per tensor
  const size_t need_bf = 3 * elems * sizeof(unsigned short);    // 12 MB
  const size_t need_full = need_bf + NCH * OUT_ELEMS * sizeof(float);  // 44 MB
  const bool use_ws = (d_ws != nullptr) && (ws_size >= need_bf);
  const bool use_part = (d_ws != nullptr) && (ws_size >= need_full);

  if (use_ws) {
    unsigned short* kb = (unsigned short*)d_ws;
    unsigned short* qb = kb + elems;
    unsigned short* vtp = qb + elems;
    cvt_bf16_kernel<<<elems / 8 / 256, 256, 0, stream>>>(k, kb);
    cvt_bf16_kernel<<<elems / 8 / 256, 256, 0, stream>>>(q, qb);
    transpose_v_kernel<<<dim3(MM / 64, DD / 64, NB), 256, 0, stream>>>(v, vtp);
    if (use_part) {
      float* partials = (float*)((char*)d_ws + need_bf);
      attn_fused<true, true><<<dim3(NN / BN * NCH), 512, 0, stream>>>(k, q, v, kb, qb, vtp,
                                                                      partials);
      reduce4_kernel<<<OUT_ELEMS / 4 / 256, 256, 0, stream>>>(partials, out);
    } else {
      zero_out_kernel<<<(NB * NN * DD) / 4 / 256, 256, 0, stream>>>((float4*)out);
      attn_fused<true, false><<<dim3(NN / BN * NCH), 512, 0, stream>>>(k, q, v, kb, qb, vtp,
                                                                       out);
    }
  } else {
    zero_out_kernel<<<(NB * NN * DD) / 4 / 256, 256, 0, stream>>>((float4*)out);
    attn_fused<false, false><<<dim3(NN / BN * NCH), 512, 0, stream>>>(k, q, v, nullptr,
                                                                      nullptr, nullptr, out);
  }
}

// Round 6
// 147.470 us; speedup vs baseline: 4.8623x; 1.0417x over previous
//
#include <hip/hip_runtime.h>
#include <hip/hip_bf16.h>

#define NB 4
#define NN 4096
#define MM 4096
#define DD 128
#define BN 32
#define BM 64
#define NCH 4   // m-chunks; grid = 128*4 = 512 blocks, XCD-pinned
#define OUT_ELEMS ((size_t)NB * NN * DD)

using f32x4  = __attribute__((ext_vector_type(4))) float;
using bf16x8 = __attribute__((ext_vector_type(8))) short;

__device__ __forceinline__ float fast_exp2(float x) {
  return __builtin_amdgcn_exp2f(x);   // v_exp_f32: D = 2^S0
}

__device__ __forceinline__ short f2bf(float x) {
  union { __hip_bfloat16 h; short s; } u;
  u.h = __float2bfloat16(x);
  return u.s;
}

__device__ __forceinline__ bf16x8 pack8(const float* __restrict__ p) {
  float4 a = *(const float4*)p;
  float4 b = *(const float4*)(p + 4);
  bf16x8 r;
  r[0] = f2bf(a.x); r[1] = f2bf(a.y); r[2] = f2bf(a.z); r[3] = f2bf(a.w);
  r[4] = f2bf(b.x); r[5] = f2bf(b.y); r[6] = f2bf(b.z); r[7] = f2bf(b.w);
  return r;
}

__global__ __launch_bounds__(256) void zero_out_kernel(float4* __restrict__ out) {
  out[(size_t)blockIdx.x * 256 + threadIdx.x] = (float4){0.f, 0.f, 0.f, 0.f};
}

__global__ __launch_bounds__(256) void cvt_bf16_kernel(const float* __restrict__ src,
                                                       unsigned short* __restrict__ dst) {
  size_t i = ((size_t)blockIdx.x * 256 + threadIdx.x) * 8;
  *(bf16x8*)(dst + i) = pack8(src + i);
}

// V[b][m][d] fp32 -> Vt[b][d][m] bf16, 64x64 tiles via LDS
__global__ __launch_bounds__(256) void transpose_v_kernel(const float* __restrict__ v,
                                                          unsigned short* __restrict__ vt) {
  __shared__ unsigned short t[64][72];
  const int b = blockIdx.z, d0 = blockIdx.y * 64, m0 = blockIdx.x * 64;
  const int r = threadIdx.x >> 2, c4 = threadIdx.x & 3;
  const float* src = v + ((size_t)b * MM + m0 + r) * DD + d0 + c4 * 16;
  for (int j = 0; j < 4; ++j) {
    float4 x = *(const float4*)(src + j * 4);
    int dl = c4 * 16 + j * 4;
    t[dl + 0][r] = (unsigned short)f2bf(x.x);
    t[dl + 1][r] = (unsigned short)f2bf(x.y);
    t[dl + 2][r] = (unsigned short)f2bf(x.z);
    t[dl + 3][r] = (unsigned short)f2bf(x.w);
  }
  __syncthreads();
  const int d = threadIdx.x >> 2, seg = threadIdx.x & 3;
  unsigned short* dst = vt + ((size_t)b * DD + d0 + d) * MM + m0 + seg * 16;
  *(bf16x8*)dst = *(bf16x8*)&t[d][seg * 16];
  *(bf16x8*)(dst + 8) = *(bf16x8*)&t[d][seg * 16 + 8];
}

// Sum the NCH partial tensors -> out
__global__ __launch_bounds__(256) void reduce4_kernel(const float* __restrict__ p,
                                                      float* __restrict__ out) {
  size_t i = ((size_t)blockIdx.x * 256 + threadIdx.x) * 4;
  float4 a = *(const float4*)(p + i);
  float4 b = *(const float4*)(p + OUT_ELEMS + i);
  float4 c = *(const float4*)(p + 2 * OUT_ELEMS + i);
  float4 d = *(const float4*)(p + 3 * OUT_ELEMS + i);
  float4 r;
  r.x = (a.x + b.x) + (c.x + d.x);
  r.y = (a.y + b.y) + (c.y + d.y);
  r.z = (a.z + b.z) + (c.z + d.z);
  r.w = (a.w + b.w) + (c.w + d.w);
  *(float4*)(out + i) = r;
}

// Raw barrier: LDS visibility only — global loads stay in flight (no vmcnt drain).
#define LGKM0_SBAR()                                        \
  do {                                                      \
    asm volatile("s_waitcnt lgkmcnt(0)" ::: "memory");      \
    __builtin_amdgcn_sched_barrier(0);                      \
    __builtin_amdgcn_s_barrier();                           \
  } while (0)

// Fused main kernel. 1-D grid, XCD-pinned (chunk = wg&3, XCD = wg&7).
// Rotated 2-barrier pipeline: QK(t0); B; { issueV(t); SM(t); B; PV(t)+QK(t+1); B }
template <bool WS, bool PART>
__global__ __launch_bounds__(512, 4) void attn_fused(
    const float* __restrict__ k, const float* __restrict__ q, const float* __restrict__ v,
    const unsigned short* __restrict__ kb, const unsigned short* __restrict__ qb,
    const unsigned short* __restrict__ vt, float* __restrict__ outp) {
  __shared__ alignas(16) float s_pos[NB][8][64][4];          // 32 KB positional exchange
  __shared__ alignas(16) unsigned short Wl[NB][BN][BM];      // 16 KB, m XOR-swizzled

  const int tid = threadIdx.x;
  const int wv = tid >> 6, l = tid & 63, lr = l & 15, hg = l >> 4;
  const int wg = blockIdx.x;
  const int cid = wg & (NCH - 1);
  const int n0 = (wg >> 2) * BN;
  const int it0 = cid * (MM / BM / NCH);
  const int it1 = it0 + (MM / BM / NCH);

  const int bq = wv >> 1, h = wv & 1;          // (batch, half) for QK/PV phases
  const int h_s = wv >> 2, fi_s = (wv >> 1) & 1, fj_s = wv & 1;  // softmax slot

  // K A-fragments (register-cached): rows n0..n0+31 of batch bq, full D
  bf16x8 ka[2][4];
  for (int fi = 0; fi < 2; ++fi)
    for (int kf = 0; kf < 4; ++kf) {
      size_t koff = ((size_t)bq * NN + n0 + fi * 16 + lr) * DD + kf * 32 + hg * 8;
      if (WS) ka[fi][kf] = *(const bf16x8*)(kb + koff);
      else    ka[fi][kf] = pack8(k + koff);
    }

  f32x4 acc[2][4];
  for (int fi = 0; fi < 2; ++fi)
    for (int dj = 0; dj < 4; ++dj) acc[fi][dj] = (f32x4){0.f, 0.f, 0.f, 0.f};

  bf16x8 vf[4][2];  // V fragments, live across one barrier

  auto do_qk = [&](int it) {
    const int m0 = it * BM;
    bf16x8 qf[2][4];
    for (int fj = 0; fj < 2; ++fj)
      for (int kf = 0; kf < 4; ++kf) {
        size_t moff = ((size_t)bq * MM + m0 + h * 32 + fj * 16 + lr) * DD + kf * 32 + hg * 8;
        if (WS) qf[fj][kf] = *(const bf16x8*)(qb + moff);
        else    qf[fj][kf] = pack8(q + moff);
      }
    f32x4 s[2][2];
    for (int fi = 0; fi < 2; ++fi)
      for (int fj = 0; fj < 2; ++fj) s[fi][fj] = (f32x4){0.f, 0.f, 0.f, 0.f};
    __builtin_amdgcn_s_setprio(1);
    for (int kf = 0; kf < 4; ++kf)
      for (int fi = 0; fi < 2; ++fi)
        for (int fj = 0; fj < 2; ++fj)
          s[fi][fj] = __builtin_amdgcn_mfma_f32_16x16x32_bf16(ka[fi][kf], qf[fj][kf],
                                                              s[fi][fj], 0, 0, 0);
    __builtin_amdgcn_s_setprio(0);
    for (int fi = 0; fi < 2; ++fi)
      for (int fj = 0; fj < 2; ++fj)
        *(f32x4*)&s_pos[bq][h * 4 + fi * 2 + fj][l][0] = s[fi][fj];
  };

  auto issue_v = [&](int it) {
    const int m0 = it * BM;
    for (int dj = 0; dj < 4; ++dj)
      for (int kf = 0; kf < 2; ++kf) {
        if (WS) {
          vf[dj][kf] = *(const bf16x8*)(vt + ((size_t)bq * DD + h * 64 + dj * 16 + lr) * MM +
                                        m0 + kf * 32 + hg * 8);
        } else {
          bf16x8 t;
          for (int e = 0; e < 8; ++e)
            t[e] = f2bf(v[((size_t)bq * MM + m0 + kf * 32 + hg * 8 + e) * DD +
                          h * 64 + dj * 16 + lr]);
          vf[dj][kf] = t;
        }
      }
  };

  auto do_sm = [&]() {
    f32x4 sv[NB];
    for (int bb = 0; bb < NB; ++bb) sv[bb] = *(f32x4*)&s_pos[bb][wv][l][0];
    const float L2E = 1.4426950408889634f;
    for (int qq = 0; qq < 4; ++qq) {
      // round 1: no max subtraction — |s| <~ 70 stays in f32 exp range
      float e0 = fast_exp2(sv[0][qq] * L2E), e1 = fast_exp2(sv[1][qq] * L2E);
      float e2 = fast_exp2(sv[2][qq] * L2E), e3 = fast_exp2(sv[3][qq] * L2E);
      float inv = __builtin_amdgcn_rcpf((e0 + e1) + (e2 + e3)) * L2E;
      // round 2: inputs in [0,1]
      float f0 = fast_exp2(e0 * inv), f1 = fast_exp2(e1 * inv);
      float f2v = fast_exp2(e2 * inv), f3 = fast_exp2(e3 * inv);
      float inv2 = __builtin_amdgcn_rcpf((f0 + f1) + (f2v + f3));
      const int n_loc = fi_s * 16 + hg * 4 + qq;          // C/D layout: row
      const int m_loc = h_s * 32 + fj_s * 16 + lr;        // C/D layout: col
      const int msw = m_loc ^ ((n_loc & 7) << 3);         // 16B-chunk XOR swizzle
      Wl[0][n_loc][msw] = (unsigned short)f2bf(f0 * inv2);
      Wl[1][n_loc][msw] = (unsigned short)f2bf(f1 * inv2);
      Wl[2][n_loc][msw] = (unsigned short)f2bf(f2v * inv2);
      Wl[3][n_loc][msw] = (unsigned short)f2bf(f3 * inv2);
    }
  };

  auto do_pv = [&]() {
    bf16x8 wf[2][2];
    for (int fi = 0; fi < 2; ++fi)
      for (int kf = 0; kf < 2; ++kf) {
        const int row = fi * 16 + lr, mo = kf * 32 + hg * 8;
        wf[fi][kf] = *(bf16x8*)&Wl[bq][row][mo ^ ((row & 7) << 3)];
      }
    __builtin_amdgcn_s_setprio(1);
    for (int kf = 0; kf < 2; ++kf)
      for (int fi = 0; fi < 2; ++fi)
        for (int dj = 0; dj < 4; ++dj)
          acc[fi][dj] = __builtin_amdgcn_mfma_f32_16x16x32_bf16(wf[fi][kf], vf[dj][kf],
                                                                acc[fi][dj], 0, 0, 0);
    __builtin_amdgcn_s_setprio(0);
  };

  // ---- rotated pipeline, 2 raw barriers per iteration ----
  do_qk(it0);
  LGKM0_SBAR();
  for (int t = it0; t < it1; ++t) {
    issue_v(t);          // V loads fly across the next barrier, land during SM
    do_sm();
    LGKM0_SBAR();
    do_pv();             // Q loads for t+1 issue at this phase, hide under PV
    if (t + 1 < it1) do_qk(t + 1);
    LGKM0_SBAR();
  }

  // ---- epilogue ----
  float* dst = PART ? (outp + (size_t)cid * OUT_ELEMS) : outp;
  for (int fi = 0; fi < 2; ++fi)
    for (int dj = 0; dj < 4; ++dj)
      for (int qq = 0; qq < 4; ++qq) {
        size_t off = ((size_t)bq * NN + n0 + fi * 16 + hg * 4 + qq) * DD +
                     h * 64 + dj * 16 + lr;
        if (PART) dst[off] = acc[fi][dj][qq];
        else      atomicAdd(dst + off, acc[fi][dj][qq]);
      }
}

extern "C" void kernel_launch(void* const* d_in, const int* in_sizes, int n_in,
                              void* d_out, int out_size, void* d_ws, size_t ws_size,
                              hipStream_t stream) {
  (void)in_sizes; (void)n_in; (void)out_size;
  const float* k = (const float*)d_in[0];
  const float* q = (const float*)d_in[1];
  const float* v = (const float*)d_in[2];
  float* out = (float*)d_out;

  const size_t elems = (size_t)NB * MM * DD;                    // 2M per tensor
  const size_t need_bf = 3 * elems * sizeof(unsigned short);    // 12 MB
  const size_t need_full = need_bf + NCH * OUT_ELEMS * sizeof(float);  // 44 MB
  const bool use_ws = (d_ws != nullptr) && (ws_size >= need_bf);
  const bool use_part = (d_ws != nullptr) && (ws_size >= need_full);

  if (use_ws) {
    unsigned short* kb = (unsigned short*)d_ws;
    unsigned short* qb = kb + elems;
    unsigned short* vtp = qb + elems;
    cvt_bf16_kernel<<<elems / 8 / 256, 256, 0, stream>>>(k, kb);
    cvt_bf16_kernel<<<elems / 8 / 256, 256, 0, stream>>>(q, qb);
    transpose_v_kernel<<<dim3(MM / 64, DD / 64, NB), 256, 0, stream>>>(v, vtp);
    if (use_part) {
      float* partials = (float*)((char*)d_ws + need_bf);
      attn_fused<true, true><<<dim3(NN / BN * NCH), 512, 0, stream>>>(k, q, v, kb, qb, vtp,
                                                                      partials);
      reduce4_kernel<<<OUT_ELEMS / 4 / 256, 256, 0, stream>>>(partials, out);
    } else {
      zero_out_kernel<<<(NB * NN * DD) / 4 / 256, 256, 0, stream>>>((float4*)out);
      attn_fused<true, false><<<dim3(NN / BN * NCH), 512, 0, stream>>>(k, q, v, kb, qb, vtp,
                                                                       out);
    }
  } else {
    zero_out_kernel<<<(NB * NN * DD) / 4 / 256, 256, 0, stream>>>((float4*)out);
    attn_fused<false, false><<<dim3(NN / BN * NCH), 512, 0, stream>>>(k, q, v, nullptr,
                                                                      nullptr, nullptr, out);
  }
}